// Round 4
// baseline (912.107 us; speedup 1.0000x reference)
//
#include <hip/hip_runtime.h>

#define EMBED  512
#define HIDDEN 1024
#define G4     4096      // 4*HIDDEN
#define VOCAB  50257
#define BATCH  64
#define TSTEPS 18
#define MROWS  (BATCH*TSTEPS)   // 1152

typedef __bf16 bf16x8 __attribute__((ext_vector_type(8)));
typedef float  f32x4  __attribute__((ext_vector_type(4)));

// ---------------- workspace layout (byte offsets) ----------------
#define WS_HA_B   0
#define WS_HB_B   131072
#define WS_BAR_B  262144
#define WS_XB_B   524288
#define WS_HS_B   1572864

#define NLSTM_BLK 64

__device__ inline bf16x8 cvt2bf8(float4 a, float4 b) {
    bf16x8 v;
    v[0] = (__bf16)a.x; v[1] = (__bf16)a.y; v[2] = (__bf16)a.z; v[3] = (__bf16)a.w;
    v[4] = (__bf16)b.x; v[5] = (__bf16)b.y; v[6] = (__bf16)b.z; v[7] = (__bf16)b.w;
    return v;
}

// ---------------- x_proj (also zeroes flag region) ----------------
__global__ __launch_bounds__(256) void k_xproj(const float* __restrict__ feat,
                                               const float* __restrict__ W_ih,
                                               const float* __restrict__ b_ih,
                                               const float* __restrict__ b_hh,
                                               float* __restrict__ xb,
                                               unsigned* __restrict__ flags) {
    if (blockIdx.x == 0 && blockIdx.y == 0) {
        #pragma unroll
        for (int k = 0; k < 8; ++k) flags[threadIdx.x * 8 + k] = 0u;
    }
    __shared__ float fsh[16][EMBED];
    const int tx = threadIdx.x;
    const int rc = blockIdx.x;
    const int b0 = blockIdx.y * 16;
    {
        int row = tx >> 4, seg = tx & 15;
        const float4* src = (const float4*)(feat + (b0 + row) * EMBED + seg * 32);
        float4* dst = (float4*)(&fsh[row][seg * 32]);
        #pragma unroll
        for (int c = 0; c < 8; ++c) dst[c] = src[c];
    }
    __syncthreads();
    const int jl = tx & 15, bl = tx >> 4;
    const int r = rc * 16 + jl;
    const int b = b0 + bl;
    const float4* w  = (const float4*)(W_ih + (size_t)r * EMBED);
    const float4* h4 = (const float4*)(&fsh[bl][0]);
    float acc = 0.f;
    #pragma unroll 4
    for (int k = 0; k < EMBED / 4; ++k) {
        float4 wv = w[k], hv = h4[k];
        acc += wv.x * hv.x + wv.y * hv.y + wv.z * hv.z + wv.w * hv.w;
    }
    xb[b * G4 + r] = acc + b_ih[r] + b_hh[r];
}

// ---------------- sc1 (agent-coherent, L1/L2-bypass) primitives ----------------
__device__ __forceinline__ void store_h_sc(__bf16* p, __bf16 v) {
    unsigned hv = (unsigned)__builtin_bit_cast(unsigned short, v);
    asm volatile("global_store_short %0, %1, off sc0 sc1" :: "v"(p), "v"(hv) : "memory");
}

#define WAIT0 asm volatile("s_waitcnt vmcnt(0)" ::: "memory")
#define WAIT4 asm volatile("s_waitcnt vmcnt(4)" ::: "memory")
#define SBAR  __builtin_amdgcn_sched_barrier(0)

// distributed-flag grid barrier (no atomics, no fences)
__device__ __forceinline__ void step_barrier(unsigned* flags, int bid, int wave,
                                             int lane, unsigned t) {
    WAIT0;
    __syncthreads();
    if (threadIdx.x == 0) {
        unsigned* fp = flags + (size_t)bid * 32;
        asm volatile("global_store_dword %0, %1, off sc0 sc1" :: "v"(fp), "v"(t) : "memory");
    }
    if (wave == 0) {
        const unsigned* pp = flags + (size_t)lane * 32;
        unsigned v;
        for (;;) {
            asm volatile("global_load_dword %0, %1, off sc0 sc1\n\t"
                         "s_waitcnt vmcnt(0)"
                         : "=&v"(v) : "v"(pp) : "memory");
            if (__all((int)(v >= t))) break;
            __builtin_amdgcn_s_sleep(1);
        }
    }
    __syncthreads();
}

#define PJT 17   // padded j-stride for partials

#define LOADS(dst, sidx) do {                                                   \
    const int _ko = (sidx) * 32;                                                \
    _Pragma("unroll")                                                           \
    for (int _i = 0; _i < 4; ++_i) {                                            \
        const __bf16* _p = aBase + (size_t)_i * 16 * HIDDEN + _ko;              \
        asm volatile("global_load_dwordx4 %0, %1, off sc0 sc1"                  \
                     : "=&v"(dst[_i]) : "v"(_p) : "memory");                    \
    } } while (0)

#define MFMAS(src, sidx) do {                                                   \
    _Pragma("unroll")                                                           \
    for (int _i = 0; _i < 4; ++_i)                                              \
        _Pragma("unroll")                                                       \
        for (int _g = 0; _g < 4; ++_g)                                          \
            acc[_i][_g] = __builtin_amdgcn_mfma_f32_16x16x32_bf16(              \
                src[_i], bB[_g][sidx], acc[_i][_g], 0, 0, 0);                   \
    } while (0)

// ---------------- fused LSTM: all 18 steps, ONE plain launch (unchanged) ----------------
__global__ __launch_bounds__(256, 1) void k_lstm(const float* __restrict__ xb,
                                                 const float* __restrict__ Whh32,
                                                 __bf16* __restrict__ hA,
                                                 __bf16* __restrict__ hB,
                                                 __bf16* __restrict__ hs,
                                                 unsigned* __restrict__ flags) {
    __shared__ float part[16 * 64 * PJT];   // 69632 B
    const int tx   = threadIdx.x;
    const int wave = tx >> 6;
    const int lane = tx & 63;
    const int q    = lane >> 4;
    const int r    = lane & 15;
    const int bid  = blockIdx.x;
    const int j0   = bid * 16;
    const int kb   = wave * 256;

    bf16x8 bB[4][8];
    {
        const float* bsrc = Whh32 + (size_t)(j0 + r) * HIDDEN + kb + q * 8;
        #pragma unroll
        for (int g = 0; g < 4; ++g)
            #pragma unroll
            for (int s = 0; s < 8; ++s) {
                const float4* p = (const float4*)(bsrc + (size_t)g * 1024 * HIDDEN + s * 32);
                bB[g][s] = cvt2bf8(p[0], p[1]);
            }
    }

    const int jl = tx & 15;
    const int m0 = tx >> 4;
    float cr[4];
    float xbr[4][4];
    #pragma unroll
    for (int mi = 0; mi < 4; ++mi) {
        cr[mi] = 0.f;
        const int m = mi * 16 + m0;
        #pragma unroll
        for (int g = 0; g < 4; ++g)
            xbr[mi][g] = xb[m * G4 + g * 1024 + j0 + jl];
    }

    #pragma unroll
    for (int mi = 0; mi < 4; ++mi) {
        const int m = mi * 16 + m0;
        const float i_ = 1.f / (1.f + expf(-xbr[mi][0]));
        const float g_ = tanhf(xbr[mi][2]);
        const float o_ = 1.f / (1.f + expf(-xbr[mi][3]));
        const float cn = i_ * g_;
        cr[mi] = cn;
        const float hn = o_ * tanhf(cn);
        const __bf16 hb = (__bf16)hn;
        store_h_sc(hB + m * HIDDEN + j0 + jl, hb);
        hs[(size_t)(m * TSTEPS + 0) * HIDDEN + j0 + jl] = hb;
    }

    #pragma unroll 1
    for (int t = 1; t < TSTEPS; ++t) {
        step_barrier(flags, bid, wave, lane, (unsigned)t);
        const __bf16* hi = (t & 1) ? hB : hA;
        __bf16*       ho = (t & 1) ? hA : hB;

        f32x4 acc[4][4];
        #pragma unroll
        for (int i = 0; i < 4; ++i)
            #pragma unroll
            for (int g = 0; g < 4; ++g)
                acc[i][g] = (f32x4){0.f, 0.f, 0.f, 0.f};

        const __bf16* aBase = hi + (size_t)r * HIDDEN + kb + q * 8;
        bf16x8 avA[4], avB[4];

        LOADS(avA, 0);
        LOADS(avB, 1);
        WAIT4; SBAR; MFMAS(avA, 0);
        LOADS(avA, 2);
        WAIT4; SBAR; MFMAS(avB, 1);
        LOADS(avB, 3);
        WAIT4; SBAR; MFMAS(avA, 2);
        LOADS(avA, 4);
        WAIT4; SBAR; MFMAS(avB, 3);
        LOADS(avB, 5);
        WAIT4; SBAR; MFMAS(avA, 4);
        LOADS(avA, 6);
        WAIT4; SBAR; MFMAS(avB, 5);
        LOADS(avB, 7);
        WAIT4; SBAR; MFMAS(avA, 6);
        WAIT0; SBAR; MFMAS(avB, 7);

        #pragma unroll
        for (int i = 0; i < 4; ++i)
            #pragma unroll
            for (int g = 0; g < 4; ++g)
                #pragma unroll
                for (int reg = 0; reg < 4; ++reg)
                    part[((wave * 4 + g) * 64 + i * 16 + q * 4 + reg) * PJT + r] = acc[i][g][reg];
        __syncthreads();

        #pragma unroll
        for (int mi = 0; mi < 4; ++mi) {
            const int m = mi * 16 + m0;
            float gsum[4];
            #pragma unroll
            for (int g = 0; g < 4; ++g) {
                float s = xbr[mi][g];
                #pragma unroll
                for (int w = 0; w < 4; ++w)
                    s += part[((w * 4 + g) * 64 + m) * PJT + jl];
                gsum[g] = s;
            }
            const float i_ = 1.f / (1.f + expf(-gsum[0]));
            const float f_ = 1.f / (1.f + expf(-gsum[1]));
            const float g_ = tanhf(gsum[2]);
            const float o_ = 1.f / (1.f + expf(-gsum[3]));
            const float cn = f_ * cr[mi] + i_ * g_;
            cr[mi] = cn;
            const float hn = o_ * tanhf(cn);
            const __bf16 hb = (__bf16)hn;
            store_h_sc(ho + m * HIDDEN + j0 + jl, hb);
            hs[(size_t)(m * TSTEPS + t) * HIDDEN + j0 + jl] = hb;
        }
        __syncthreads();
    }
}

// ---------------- classifier GEMM v2: BK=64 dbuf, 1 barrier/K-step ----------------
#define BKF  64
#define NBLK 393    // ceil(50257/128)
#define MBLK 9      // 1152/128
#define NWG  (NBLK*MBLK)   // 3537
#define XQ   (NWG/8)       // 442
#define XR   (NWG%8)       // 1

__global__ __launch_bounds__(256) void k_fc(const __bf16* __restrict__ hs,
                                            const float* __restrict__ W_fc,
                                            const float* __restrict__ b_fc,
                                            float* __restrict__ out) {
    // 64KB: As[2][128][64] + Bs[2][128][64] bf16 (rotation-swizzled rows);
    // epilogue overlays Ct[32][128] f32 on the same memory.
    __shared__ __align__(16) char smem[65536];
    __bf16* As = (__bf16*)smem;
    __bf16* Bs = (__bf16*)(smem + 32768);
    float*  Ct = (float*)smem;

    const int tx  = threadIdx.x;
    const int bid = blockIdx.x;
    // bijective XCD swizzle (m204): 9 m-blocks sharing one W_fc chunk -> one XCD
    const int xcd = bid & 7;
    const int lid = bid >> 3;
    const int base = (xcd < XR) ? xcd * (XQ + 1) : XR * (XQ + 1) + (xcd - XR) * XQ;
    const int virt = base + lid;
    const int mb = (virt % MBLK) * 128;
    const int nb = (virt / MBLK) * 128;

    const int lane = tx & 63;
    const int wave = tx >> 6;
    const int q = lane >> 4;
    const int r = lane & 15;
    const int wm = (wave >> 1) * 64;
    const int wn = (wave & 1) * 64;

    // staging: thread -> (row = tx>>1, k-half = tx&1), 64B of A + 128B of B
    const int srow = tx >> 1;
    const int half = tx & 1;
    const __bf16* aSrc = hs + (size_t)(mb + srow) * HIDDEN + half * 32;
    const int nclamp = min(nb + srow, VOCAB - 1);
    const float* bSrc = W_fc + (size_t)nclamp * HIDDEN + half * 32;
    __bf16* aD = As + srow * BKF;
    __bf16* bD = Bs + srow * BKF;

    bf16x8 aR[4];
    float4 bR[8];

#define FC_LOAD(k0) do {                                                        \
    _Pragma("unroll")                                                           \
    for (int cc = 0; cc < 4; ++cc)                                              \
        aR[cc] = *(const bf16x8*)(aSrc + (k0) + cc * 8);                        \
    _Pragma("unroll")                                                           \
    for (int cc = 0; cc < 8; ++cc)                                              \
        bR[cc] = *(const float4*)(bSrc + (k0) + cc * 4);                        \
} while (0)

#define FC_STAGE(buf) do {                                                      \
    _Pragma("unroll")                                                           \
    for (int cc = 0; cc < 4; ++cc) {                                            \
        const int slot = (half * 4 + cc + srow) & 7;                            \
        *(bf16x8*)(aD + (buf) * 8192 + slot * 8) = aR[cc];                      \
        *(bf16x8*)(bD + (buf) * 8192 + slot * 8) = cvt2bf8(bR[cc*2], bR[cc*2+1]); \
    }                                                                           \
} while (0)

    f32x4 acc[4][4];
    #pragma unroll
    for (int i = 0; i < 4; ++i)
        #pragma unroll
        for (int j = 0; j < 4; ++j)
            acc[i][j] = (f32x4){0.f, 0.f, 0.f, 0.f};

    FC_LOAD(0);
    FC_STAGE(0);
    __syncthreads();

    for (int kt = 0; kt < 16; ++kt) {
        const int cur = kt & 1;
        if (kt < 15) FC_LOAD((kt + 1) * BKF);   // issue early: hides under MFMA
        const __bf16* Ab = As + cur * 8192;
        const __bf16* Bb = Bs + cur * 8192;
        #pragma unroll
        for (int kk = 0; kk < 2; ++kk) {
            bf16x8 av[4], bv[4];
            #pragma unroll
            for (int i = 0; i < 4; ++i) {
                const int row = wm + i * 16 + r;
                av[i] = *(const bf16x8*)(Ab + row * BKF + ((kk * 4 + q + row) & 7) * 8);
            }
            #pragma unroll
            for (int j = 0; j < 4; ++j) {
                const int row = wn + j * 16 + r;
                bv[j] = *(const bf16x8*)(Bb + row * BKF + ((kk * 4 + q + row) & 7) * 8);
            }
            #pragma unroll
            for (int i = 0; i < 4; ++i)
                #pragma unroll
                for (int j = 0; j < 4; ++j)
                    acc[i][j] = __builtin_amdgcn_mfma_f32_16x16x32_bf16(av[i], bv[j], acc[i][j], 0, 0, 0);
        }
        if (kt < 15) FC_STAGE(cur ^ 1);   // write OTHER buffer: no LDS WAR
        __syncthreads();                   // single barrier per K-step
    }

    // ---- epilogue: LDS-transpose so each store is a 256B contiguous wave-run
    const int v0 = nb + lane;
    const int v1 = nb + 64 + lane;
    float bias0 = 0.f, bias1 = 0.f;
    if (v0 < VOCAB) bias0 = b_fc[v0];
    if (v1 < VOCAB) bias1 = b_fc[v1];

    #pragma unroll
    for (int i = 0; i < 4; ++i) {
        // stage this i-chunk's 32 rows x 128 cols into Ct
        #pragma unroll
        for (int j = 0; j < 4; ++j)
            #pragma unroll
            for (int reg = 0; reg < 4; ++reg)
                Ct[((wave >> 1) * 16 + q * 4 + reg) * 128 + wn + j * 16 + r] = acc[i][j][reg];
        __syncthreads();
        #pragma unroll
        for (int rr8 = 0; rr8 < 8; ++rr8) {
            const int rr = wave * 8 + rr8;
            const int m = mb + ((rr < 16) ? (i * 16 + rr) : (48 + i * 16 + rr));
            const float cA = Ct[rr * 128 + lane];
            const float cB = Ct[rr * 128 + 64 + lane];
            if (v0 < VOCAB) out[(size_t)m * VOCAB + v0] = cA + bias0;
            if (v1 < VOCAB) out[(size_t)m * VOCAB + v1] = cB + bias1;
        }
        __syncthreads();   // Ct fully consumed before next i overwrites
    }
#undef FC_LOAD
#undef FC_STAGE
}

extern "C" void kernel_launch(void* const* d_in, const int* in_sizes, int n_in,
                              void* d_out, int out_size, void* d_ws, size_t ws_size,
                              hipStream_t stream) {
    const float* feat = (const float*)d_in[0];
    const float* W_ih = (const float*)d_in[1];
    const float* W_hh = (const float*)d_in[2];
    const float* b_ih = (const float*)d_in[3];
    const float* b_hh = (const float*)d_in[4];
    const float* W_fc = (const float*)d_in[5];
    const float* b_fc = (const float*)d_in[6];
    float* out = (float*)d_out;

    char* wsb = (char*)d_ws;
    __bf16*   hA    = (__bf16*)(wsb + WS_HA_B);
    __bf16*   hB    = (__bf16*)(wsb + WS_HB_B);
    unsigned* flags = (unsigned*)(wsb + WS_BAR_B);
    float*    xb    = (float*)(wsb + WS_XB_B);
    __bf16*   hs    = (__bf16*)(wsb + WS_HS_B);

    k_xproj<<<dim3(256, 4), 256, 0, stream>>>(feat, W_ih, b_ih, b_hh, xb, flags);
    k_lstm<<<NLSTM_BLK, 256, 0, stream>>>(xb, W_hh, hA, hB, hs, flags);
    k_fc<<<NWG, 256, 0, stream>>>(hs, W_fc, b_fc, out);
}